// Round 10
// baseline (291.170 us; speedup 1.0000x reference)
//
#include <hip/hip_runtime.h>

#define BATCH 65536
#define HID   512
#define NCLS  1000
#define NCLSP 1024

typedef long i64;   // 8 packed fp8 (2 VGPRs) for MFMA A/B operands
typedef float f32x4 __attribute__((ext_vector_type(4)));
typedef float f32x2 __attribute__((ext_vector_type(2)));
typedef unsigned short u16;
typedef unsigned int u32;
typedef unsigned char u8;

__device__ __forceinline__ u16 f2bf(float f) {
  u32 u = __float_as_uint(f);
  u += 0x7fffu + ((u >> 16) & 1u);
  return (u16)(u >> 16);
}

// pack 4 floats -> 4 fp8 e4m3 bytes (k-order a,b,c,d)
__device__ __forceinline__ u32 pk4(float a, float b, float c, float d) {
  u32 r = 0;
  r = (u32)__builtin_amdgcn_cvt_pk_fp8_f32(a, b, (int)r, false);
  r = (u32)__builtin_amdgcn_cvt_pk_fp8_f32(c, d, (int)r, true);
  return r;
}
__device__ __forceinline__ u8 pk1(float a) {
  return (u8)(__builtin_amdgcn_cvt_pk_fp8_f32(a, 0.f, 0, false) & 0xff);
}

// ---------------- ws layout ----------------
// counts  int[1024]        @ 0
// accum   double[8]        @ 4096   (0 stab, 1 center, 2 sep, 3 brier)
// sq      float[1024]      @ 8192
// offsets int[1024]        @ 12288  (after k_scatter: segment END)
// order   int[65536]       @ 16384
// centers float[1024*512]  @ 278528
// wb8     u8[16*1024*32]   @ 2375680  (frag-linear fp8 of 16*W; 512 KB)
// panel8  u8[65536*512]    @ 2899968  (pre-swizzled fp8 cls+0.1*noise; 32 MB)
#define WS_END 2899968
#define WS_BIG 36454400

// ---------------- zero counts + accum (replaces hipMemsetAsync: the 4 KB
// memset node was measured at ~155 us/replay in the graph — rounds 1-9!) ----------------
__global__ void k_zero(int* __restrict__ counts, double* __restrict__ accum) {
  const int t = threadIdx.x;
  counts[t] = 0;
  if (t < 8) accum[t] = 0.0;
}

// ---------------- label histogram ----------------
__global__ void k_hist(const int* __restrict__ labels, int* __restrict__ counts) {
  const int i = blockIdx.x * blockDim.x + threadIdx.x;
  if (i < BATCH) atomicAdd(counts + labels[i], 1);
}

// ---------------- exclusive prefix sum over 1024 bins (1 block) ----------------
__global__ void k_scan(const int* __restrict__ counts, int* __restrict__ offsets) {
  __shared__ int tmp[1024];
  const int t = threadIdx.x;
  const int v = counts[t];
  tmp[t] = v;
  __syncthreads();
  for (int d = 1; d < 1024; d <<= 1) {
    int u = (t >= d) ? tmp[t - d] : 0;
    __syncthreads();
    tmp[t] += u;
    __syncthreads();
  }
  offsets[t] = tmp[t] - v;   // exclusive
}

// ---------------- scatter row indices into class-sorted order ----------------
__global__ void k_scatter(const int* __restrict__ labels, int* __restrict__ offsets,
                          int* __restrict__ order) {
  const int i = blockIdx.x * blockDim.x + threadIdx.x;
  if (i < BATCH) {
    const int pos = atomicAdd(offsets + labels[i], 1);
    order[pos] = i;
  }
}

// ---------------- segmented mean -> centers, |center|^2, center-loss (single pass) ----------------
// center loss per (class, col): sum(x - c)^2 = sum(x^2) - cnt * c^2
__global__ void k_segsum(const float* __restrict__ cls, const int* __restrict__ order,
                         const int* __restrict__ offsets, const int* __restrict__ counts,
                         const float* __restrict__ cen_in, float* __restrict__ cen,
                         float* __restrict__ sq, double* __restrict__ accum) {
  __shared__ float red[8];
  __shared__ float redc[8];
  const int c = blockIdx.x;     // 0..1023
  const int t = threadIdx.x;    // 0..511 (one column each)
  const int cnt = counts[c];
  const int end = offsets[c];   // after scatter, offsets[c] == segment end
  const int start = end - cnt;
  float v, cp;
  if (cnt > 0) {
    float s0 = 0.f, s1 = 0.f, s2 = 0.f, s3 = 0.f;
    float q0 = 0.f, q1 = 0.f, q2 = 0.f, q3 = 0.f;
    int i = start;
    for (; i + 4 <= end; i += 4) {
      const int r0 = order[i], r1 = order[i + 1], r2 = order[i + 2], r3 = order[i + 3];
      float x0 = cls[(size_t)r0 * HID + t];
      float x1 = cls[(size_t)r1 * HID + t];
      float x2 = cls[(size_t)r2 * HID + t];
      float x3 = cls[(size_t)r3 * HID + t];
      s0 += x0; q0 = fmaf(x0, x0, q0);
      s1 += x1; q1 = fmaf(x1, x1, q1);
      s2 += x2; q2 = fmaf(x2, x2, q2);
      s3 += x3; q3 = fmaf(x3, x3, q3);
    }
    for (; i < end; ++i) {
      float x = cls[(size_t)order[i] * HID + t];
      s0 += x; q0 = fmaf(x, x, q0);
    }
    v = ((s0 + s1) + (s2 + s3)) / (float)cnt;
    cp = ((q0 + q1) + (q2 + q3)) - (float)cnt * v * v;
  } else {
    v = (c < NCLS) ? cen_in[(size_t)c * HID + t] : 0.f;
    cp = 0.f;
  }
  cen[(size_t)c * HID + t] = v;

  float p = v * v;
  #pragma unroll
  for (int s = 32; s; s >>= 1) { p += __shfl_xor(p, s); cp += __shfl_xor(cp, s); }
  if ((t & 63) == 0) { red[t >> 6] = p; redc[t >> 6] = cp; }
  __syncthreads();
  if (t == 0) {
    float acc = 0.f, accc = 0.f;
    #pragma unroll
    for (int i = 0; i < 8; ++i) { acc += red[i]; accc += redc[i]; }
    sq[c] = acc;
    atomicAdd(accum + 1, (double)accc);
  }
}

// ---------------- W f32 -> fragment-linear fp8 (scaled x16) ----------------
__global__ void k_wconv(const float* __restrict__ W, u32* __restrict__ wb) {
  const int j = blockIdx.x * blockDim.x + threadIdx.x;   // 131072 total
  const int kc = j >> 13, col = (j >> 3) & 1023, kg = (j >> 1) & 3, i0 = (j & 1) * 4;
  const int k = kc * 32 + kg * 8 + i0;
  float w0 = 0.f, w1 = 0.f, w2 = 0.f, w3 = 0.f;
  if (col < NCLS) {
    w0 = W[(size_t)(k + 0) * NCLS + col] * 16.f;
    w1 = W[(size_t)(k + 1) * NCLS + col] * 16.f;
    w2 = W[(size_t)(k + 2) * NCLS + col] * 16.f;
    w3 = W[(size_t)(k + 3) * NCLS + col] * 16.f;
  }
  wb[j] = pk4(w0, w1, w2, w3);
}

// ---------------- separation: Gram + exp-sum ----------------
__global__ void k_sep(const float* __restrict__ cen, const float* __restrict__ sq,
                      double* __restrict__ accum) {
  __shared__ float As[16][64];
  __shared__ float Bs[16][64];
  __shared__ float red[4];
  const int bi = blockIdx.x >> 4, bj = blockIdx.x & 15;
  const int tx = threadIdx.x & 15, ty = threadIdx.x >> 4;
  const int lrow = threadIdx.x & 63, lkq = threadIdx.x >> 6;
  float acc[4][4] = {};
  for (int k0 = 0; k0 < HID; k0 += 16) {
    __syncthreads();
    float4 a = *(const float4*)(cen + (size_t)(bi * 64 + lrow) * HID + k0 + lkq * 4);
    float4 b = *(const float4*)(cen + (size_t)(bj * 64 + lrow) * HID + k0 + lkq * 4);
    As[lkq*4+0][lrow] = a.x; As[lkq*4+1][lrow] = a.y; As[lkq*4+2][lrow] = a.z; As[lkq*4+3][lrow] = a.w;
    Bs[lkq*4+0][lrow] = b.x; Bs[lkq*4+1][lrow] = b.y; Bs[lkq*4+2][lrow] = b.z; Bs[lkq*4+3][lrow] = b.w;
    __syncthreads();
    #pragma unroll
    for (int k = 0; k < 16; ++k) {
      float4 av = *(const float4*)&As[k][ty * 4];
      float4 bv = *(const float4*)&Bs[k][tx * 4];
      float ar[4] = {av.x, av.y, av.z, av.w};
      float br[4] = {bv.x, bv.y, bv.z, bv.w};
      #pragma unroll
      for (int r = 0; r < 4; ++r)
        #pragma unroll
        for (int s = 0; s < 4; ++s)
          acc[r][s] = fmaf(ar[r], br[s], acc[r][s]);
    }
  }
  float part = 0.f;
  #pragma unroll
  for (int r = 0; r < 4; ++r) {
    const int i = bi * 64 + ty * 4 + r;
    #pragma unroll
    for (int s = 0; s < 4; ++s) {
      const int j = bj * 64 + tx * 4 + s;
      if (i < NCLS && j < NCLS) {
        float d2 = fmaxf(sq[i] + sq[j] - 2.f * acc[r][s], 0.f);
        float dist = sqrtf(d2);
        part += __expf((i == j ? 1.f : 0.f) - dist);
      }
    }
  }
  #pragma unroll
  for (int s = 32; s; s >>= 1) part += __shfl_xor(part, s);
  if ((threadIdx.x & 63) == 0) red[threadIdx.x >> 6] = part;
  __syncthreads();
  if (threadIdx.x == 0)
    atomicAdd(accum + 2, (double)(red[0] + red[1] + red[2] + red[3]));
}

// ---------------- prep: fp8 panel x = cls + 0.1*noise, pre-swizzled ----------------
__global__ void k_prep(const float* __restrict__ cls, const float* __restrict__ noise,
                       u8* __restrict__ panel) {
  const int nth = gridDim.x * blockDim.x;
  for (int c = blockIdx.x * blockDim.x + threadIdx.x; c < BATCH * 64; c += nth) {
    const int row = c >> 6;
    const int g = (c & 63) * 8;                 // dest granule (8 bytes)
    const int sw = ((row & 7) << 3) | (((row >> 3) & 1) << 6);
    const int k = g ^ sw;                       // source k
    const float4* cp = (const float4*)(cls   + (size_t)row * HID + k);
    const float4* np = (const float4*)(noise + (size_t)row * HID + k);
    float4 a0 = cp[0], a1 = cp[1];
    float4 n0 = np[0], n1 = np[1];
    uint2 p;
    p.x = pk4(fmaf(0.1f, n0.x, a0.x), fmaf(0.1f, n0.y, a0.y),
              fmaf(0.1f, n0.z, a0.z), fmaf(0.1f, n0.w, a0.w));
    p.y = pk4(fmaf(0.1f, n1.x, a1.x), fmaf(0.1f, n1.y, a1.y),
              fmaf(0.1f, n1.z, a1.z), fmaf(0.1f, n1.w, a1.w));
    *(uint2*)&panel[(size_t)row * 512 + g] = p;
  }
}

// ---------------- fused GEMM (fp8 MFMA) + fp8 ln tile + stab/brier epilogue ----------------
// BM=32 rows/block (2048 blocks), BN=1024, 16 waves x 64 cols, acc[2][4]=32 f32/lane.
// __launch_bounds__(1024,8): cap 64 unified regs -> 2 blocks (32 waves)/CU. LDS 48 KB.
__global__ __launch_bounds__(1024, 8)
void k_gemm(const u8* __restrict__ panel, const float* __restrict__ logits,
            const int* __restrict__ labels, const float* __restrict__ bias,
            const u8* __restrict__ wb, double* __restrict__ accum) {
  __shared__ u8 Apan[32 * 512];      // 16 KB fp8 A-panel (pre-swizzled)
  __shared__ u8 lntile[32 * 1024];   // 32 KB fp8 ln tile (disjoint from Apan)
  __shared__ float redf[32];
  const int lane = threadIdx.x & 63;
  const int w = threadIdx.x >> 6;    // 0..15
  const int row0 = blockIdx.x * 32;
  const int l15 = lane & 15, lkg = lane >> 4;

  // ---- phase 1: DMA the pre-swizzled 32x512 fp8 tile into LDS (width-16) ----
  {
    const u8* g = panel + (size_t)blockIdx.x * 16384 + w * 1024 + lane * 16;
    u8* l = Apan + w * 1024;
    __builtin_amdgcn_global_load_lds((const __attribute__((address_space(1))) void*)g,
                                     (__attribute__((address_space(3))) void*)l,
                                     16, 0, 0);
  }
  __syncthreads();

  // ---- phase 2: 16 barrier-free K-steps (fp8), 64 cols/wave ----
  f32x4 acc[2][4] = {};
  const int swr = ((l15 & 7) << 3) | ((l15 >> 3) << 6);
  for (int kc = 0; kc < 16; ++kc) {
    i64 af0 = *(const i64*)&Apan[(l15)      * 512 + ((kc * 32 + lkg * 8) ^ swr)];
    i64 af1 = *(const i64*)&Apan[(16 + l15) * 512 + ((kc * 32 + lkg * 8) ^ swr)];
    const u8* bb = wb + (size_t)kc * 32768 + (w * 64 + l15) * 32 + lkg * 8;
    #pragma unroll
    for (int ct = 0; ct < 4; ++ct) {
      i64 bf = *(const i64*)(bb + ct * 512);
      acc[0][ct] = __builtin_amdgcn_mfma_f32_16x16x32_fp8_fp8(af0, bf, acc[0][ct], 0, 0, 0);
      acc[1][ct] = __builtin_amdgcn_mfma_f32_16x16x32_fp8_fp8(af1, bf, acc[1][ct], 0, 0, 0);
    }
  }

  // ---- phase 3a: ln = acc/16 + bias -> fp8 into lntile ----
  #pragma unroll
  for (int ct = 0; ct < 4; ++ct) {
    const int col = w * 64 + ct * 16 + l15;
    if (col < NCLS) {
      const float bc = bias[col];
      #pragma unroll
      for (int rt = 0; rt < 2; ++rt) {
        #pragma unroll
        for (int r = 0; r < 4; ++r) {
          const int rowloc = rt * 16 + lkg * 4 + r;
          lntile[rowloc * 1024 + (col ^ ((rowloc & 12) << 2))] =
              pk1(fmaf(acc[rt][ct][r], 0.0625f, bc));
        }
      }
    }
  }
  __syncthreads();

  // ---- phase 3b: single coalesced pass over logits: diff^2 + brier (no max-sub) ----
  float spart = 0.f, bpart = 0.f;
  #pragma unroll
  for (int j = 0; j < 2; ++j) {
    const int rowloc = w * 2 + j;
    const int row = row0 + rowloc;
    const int swz = (rowloc & 12) << 2;
    const u8* lnrow = lntile + rowloc * 1024;
    const float4* lr = (const float4*)(logits + (size_t)row * NCLS);
    const int lab2 = labels[row];
    float S = 0.f, S2 = 0.f, el = 0.f;
    #pragma unroll
    for (int it = 0; it < 4; ++it) {
      const int f = it * 64 + lane;
      if (f < 250) {
        float4 lg = lr[f];
        u32 v = *(const u32*)(lnrow + ((f * 4) ^ swz));
        f32x2 lo = __builtin_amdgcn_cvt_pk_f32_fp8((int)v, false);
        f32x2 hi = __builtin_amdgcn_cvt_pk_f32_fp8((int)v, true);
        float d0 = lo[0] - lg.x, d1 = lo[1] - lg.y, d2 = hi[0] - lg.z, d3 = hi[1] - lg.w;
        spart += d0 * d0 + d1 * d1 + d2 * d2 + d3 * d3;
        float e0 = __expf(lg.x), e1 = __expf(lg.y), e2 = __expf(lg.z), e3 = __expf(lg.w);
        S += e0 + e1 + e2 + e3;
        S2 += e0 * e0 + e1 * e1 + e2 * e2 + e3 * e3;
        const int c0 = f * 4;
        if (c0     == lab2) el = e0;
        if (c0 + 1 == lab2) el = e1;
        if (c0 + 2 == lab2) el = e2;
        if (c0 + 3 == lab2) el = e3;
      }
    }
    #pragma unroll
    for (int s = 32; s; s >>= 1) { S += __shfl_xor(S, s); S2 += __shfl_xor(S2, s); el += __shfl_xor(el, s); }
    bpart += S2 / (S * S) - 2.f * el / S + 1.f;
  }
  #pragma unroll
  for (int s = 32; s; s >>= 1) { spart += __shfl_xor(spart, s); bpart += __shfl_xor(bpart, s); }

  if (lane == 0) { redf[w] = spart; redf[16 + w] = bpart; }
  __syncthreads();
  if (threadIdx.x == 0) {
    float st = 0.f, br = 0.f;
    #pragma unroll
    for (int i = 0; i < 16; ++i) { st += redf[i]; br += redf[16 + i]; }
    atomicAdd(accum + 0, (double)st);
    atomicAdd(accum + 3, (double)br);
  }
}

// ---------------- fallback: fused variant with in-kernel staging (ws < WS_BIG) ----------------
__global__ __launch_bounds__(512, 4)
void k_stab_fb(const float* __restrict__ cls, const float* __restrict__ noise,
               const float* __restrict__ logits, const int* __restrict__ labels,
               const float* __restrict__ bias, const u8* __restrict__ wb,
               double* __restrict__ accum) {
  __shared__ u16 lds[32 * 1024];
  u8* lds8 = (u8*)lds;
  const int lane = threadIdx.x & 63;
  const int w = threadIdx.x >> 6;
  const int row0 = blockIdx.x * 32;
  const int l15 = lane & 15, lkg = lane >> 4;
  {
    const int row_loc = threadIdx.x >> 4;
    const int k0 = (threadIdx.x & 15) * 32;
    const int sw = ((row_loc & 7) << 3) | (((row_loc >> 3) & 1) << 6);
    const float* cp = cls   + (size_t)(row0 + row_loc) * HID;
    const float* np = noise + (size_t)(row0 + row_loc) * HID;
    #pragma unroll
    for (int q = 0; q < 4; ++q) {
      const int g = k0 + q * 8;
      const int k = g ^ sw;
      float4 a0 = *(const float4*)(cp + k), a1 = *(const float4*)(cp + k + 4);
      float4 n0 = *(const float4*)(np + k), n1 = *(const float4*)(np + k + 4);
      uint2 p;
      p.x = pk4(fmaf(0.1f, n0.x, a0.x), fmaf(0.1f, n0.y, a0.y),
                fmaf(0.1f, n0.z, a0.z), fmaf(0.1f, n0.w, a0.w));
      p.y = pk4(fmaf(0.1f, n1.x, a1.x), fmaf(0.1f, n1.y, a1.y),
                fmaf(0.1f, n1.z, a1.z), fmaf(0.1f, n1.w, a1.w));
      *(uint2*)&lds8[row_loc * 512 + g] = p;
    }
  }
  __syncthreads();
  f32x4 acc[2][8] = {};
  const int swr = ((l15 & 7) << 3) | ((l15 >> 3) << 6);
  for (int kc = 0; kc < 16; ++kc) {
    i64 af0 = *(const i64*)&lds8[(l15)      * 512 + ((kc * 32 + lkg * 8) ^ swr)];
    i64 af1 = *(const i64*)&lds8[(16 + l15) * 512 + ((kc * 32 + lkg * 8) ^ swr)];
    const u8* bb = wb + (size_t)kc * 32768 + (w * 128 + l15) * 32 + lkg * 8;
    #pragma unroll
    for (int ct = 0; ct < 8; ++ct) {
      i64 bf = *(const i64*)(bb + ct * 512);
      acc[0][ct] = __builtin_amdgcn_mfma_f32_16x16x32_fp8_fp8(af0, bf, acc[0][ct], 0, 0, 0);
      acc[1][ct] = __builtin_amdgcn_mfma_f32_16x16x32_fp8_fp8(af1, bf, acc[1][ct], 0, 0, 0);
    }
  }
  __syncthreads();
  char* ldsb = (char*)lds;
  #pragma unroll
  for (int ct = 0; ct < 8; ++ct) {
    const int col = w * 128 + ct * 16 + l15;
    if (col < NCLS) {
      const float bc = bias[col];
      #pragma unroll
      for (int rt = 0; rt < 2; ++rt) {
        #pragma unroll
        for (int r = 0; r < 4; ++r) {
          const int rowloc = rt * 16 + lkg * 4 + r;
          const int byte = rowloc * 2048 + ((col * 2) ^ ((rowloc & 12) << 3));
          *(u16*)(ldsb + byte) = f2bf(fmaf(acc[rt][ct][r], 0.0625f, bc));
        }
      }
    }
  }
  __syncthreads();
  float spart = 0.f, bpart = 0.f;
  for (int j = 0; j < 4; ++j) {
    const int rowloc = w * 4 + j;
    const int row = row0 + rowloc;
    const int swz = (rowloc & 12) << 3;
    const char* lnrow = ldsb + rowloc * 2048;
    const float4* lr = (const float4*)(logits + (size_t)row * NCLS);
    const int lab2 = labels[row];
    float S = 0.f, S2 = 0.f, el = 0.f;
    #pragma unroll
    for (int it = 0; it < 4; ++it) {
      const int f = it * 64 + lane;
      if (f < 250) {
        float4 lg = lr[f];
        const u32* lp = (const u32*)(lnrow + ((f * 8) ^ swz));
        u32 w0 = lp[0], w1 = lp[1];
        float n0 = __uint_as_float(w0 << 16);
        float n1 = __uint_as_float(w0 & 0xffff0000u);
        float n2 = __uint_as_float(w1 << 16);
        float n3 = __uint_as_float(w1 & 0xffff0000u);
        float d0 = n0 - lg.x, d1 = n1 - lg.y, d2 = n2 - lg.z, d3 = n3 - lg.w;
        spart += d0 * d0 + d1 * d1 + d2 * d2 + d3 * d3;
        float e0 = __expf(lg.x), e1 = __expf(lg.y), e2 = __expf(lg.z), e3 = __expf(lg.w);
        S += e0 + e1 + e2 + e3;
        S2 += e0 * e0 + e1 * e1 + e2 * e2 + e3 * e3;
        const int c0 = f * 4;
        if (c0     == lab2) el = e0;
        if (c0 + 1 == lab2) el = e1;
        if (c0 + 2 == lab2) el = e2;
        if (c0 + 3 == lab2) el = e3;
      }
    }
    #pragma unroll
    for (int s = 32; s; s >>= 1) { S += __shfl_xor(S, s); S2 += __shfl_xor(S2, s); el += __shfl_xor(el, s); }
    bpart += S2 / (S * S) - 2.f * el / S + 1.f;
  }
  #pragma unroll
  for (int s = 32; s; s >>= 1) { spart += __shfl_xor(spart, s); bpart += __shfl_xor(bpart, s); }
  __syncthreads();
  float* redf = (float*)lds;
  if (lane == 0) { redf[w] = spart; redf[8 + w] = bpart; }
  __syncthreads();
  if (threadIdx.x == 0) {
    float st = 0.f, br = 0.f;
    #pragma unroll
    for (int i = 0; i < 8; ++i) { st += redf[i]; br += redf[8 + i]; }
    atomicAdd(accum + 0, (double)st);
    atomicAdd(accum + 3, (double)br);
  }
}

// ---------------- combine ----------------
__global__ void k_final(const double* __restrict__ accum, float* __restrict__ out) {
  if (threadIdx.x == 0) {
    double stab   = accum[0] / ((double)BATCH * (double)NCLS);
    double center = accum[1] / ((double)BATCH * (double)HID);
    double sep    = accum[2] - (double)NCLS;
    double brier  = accum[3] / (double)BATCH;
    double total  = 1.0 * stab + 0.1 * center + 0.01 * sep + 1.0 * brier;
    out[0] = (float)total;
    out[1] = (float)stab;
    out[2] = (float)center;
    out[3] = (float)sep;
    out[4] = (float)brier;
  }
}

extern "C" void kernel_launch(void* const* d_in, const int* in_sizes, int n_in,
                              void* d_out, int out_size, void* d_ws, size_t ws_size,
                              hipStream_t stream) {
  const float* cls    = (const float*)d_in[0];
  const float* logits = (const float*)d_in[1];
  const int*   labels = (const int*)d_in[2];
  const float* W      = (const float*)d_in[3];
  const float* bias   = (const float*)d_in[4];
  const float* noise  = (const float*)d_in[5];
  const float* cen_in = (const float*)d_in[6];
  float* out = (float*)d_out;
  char* ws = (char*)d_ws;
  if (ws_size < (size_t)WS_END) return;  // fail visibly (out stays poisoned)

  int*    counts  = (int*)(ws + 0);
  double* accum   = (double*)(ws + 4096);
  float*  sq      = (float*)(ws + 8192);
  int*    offsets = (int*)(ws + 12288);
  int*    order   = (int*)(ws + 16384);
  float*  cen     = (float*)(ws + 278528);
  u8*     wb8     = (u8*)(ws + 2375680);
  u8*     panel8  = (u8*)(ws + 2899968);

  hipLaunchKernelGGL(k_zero,    dim3(1),    dim3(1024),0, stream, counts, accum);
  hipLaunchKernelGGL(k_hist,    dim3(256),  dim3(256), 0, stream, labels, counts);
  hipLaunchKernelGGL(k_wconv,   dim3(512),  dim3(256), 0, stream, W, (u32*)wb8);
  hipLaunchKernelGGL(k_scan,    dim3(1),    dim3(1024),0, stream, counts, offsets);
  hipLaunchKernelGGL(k_scatter, dim3(256),  dim3(256), 0, stream, labels, offsets, order);
  hipLaunchKernelGGL(k_segsum,  dim3(1024), dim3(512), 0, stream, cls, order, offsets, counts, cen_in, cen, sq, accum);
  hipLaunchKernelGGL(k_sep,     dim3(256),  dim3(256), 0, stream, cen, sq, accum);
  if (ws_size >= (size_t)WS_BIG) {
    hipLaunchKernelGGL(k_prep,  dim3(2048), dim3(256), 0, stream, cls, noise, panel8);
    hipLaunchKernelGGL(k_gemm,  dim3(2048), dim3(1024), 0, stream, panel8, logits, labels, bias, wb8, accum);
  } else {
    hipLaunchKernelGGL(k_stab_fb, dim3(2048), dim3(512), 0, stream, cls, noise, logits, labels, bias, wb8, accum);
  }
  hipLaunchKernelGGL(k_final,   dim3(1),    dim3(64),  0, stream, accum, out);
}

// Round 11
// 278.458 us; speedup vs baseline: 1.0457x; 1.0457x over previous
//
#include <hip/hip_runtime.h>

#define BATCH 65536
#define HID   512
#define NCLS  1000
#define NCLSP 1024

typedef long i64;   // 8 packed fp8 (2 VGPRs) for MFMA A/B operands
typedef float f32x4 __attribute__((ext_vector_type(4)));
typedef float f32x2 __attribute__((ext_vector_type(2)));
typedef unsigned short u16;
typedef unsigned int u32;
typedef unsigned char u8;

__device__ __forceinline__ u16 f2bf(float f) {
  u32 u = __float_as_uint(f);
  u += 0x7fffu + ((u >> 16) & 1u);
  return (u16)(u >> 16);
}

// pack 4 floats -> 4 fp8 e4m3 bytes (k-order a,b,c,d)
__device__ __forceinline__ u32 pk4(float a, float b, float c, float d) {
  u32 r = 0;
  r = (u32)__builtin_amdgcn_cvt_pk_fp8_f32(a, b, (int)r, false);
  r = (u32)__builtin_amdgcn_cvt_pk_fp8_f32(c, d, (int)r, true);
  return r;
}
__device__ __forceinline__ u8 pk1(float a) {
  return (u8)(__builtin_amdgcn_cvt_pk_fp8_f32(a, 0.f, 0, false) & 0xff);
}

// ---------------- ws layout ----------------
// counts  int[1024]        @ 0
// accum   double[8]        @ 4096   (0 stab, 1 center, 2 sep, 3 brier)
// sq      float[1024]      @ 8192
// offsets int[1024]        @ 12288  (after k_scatter: segment END)
// order   int[65536]       @ 16384
// centers float[1024*512]  @ 278528
// wb8     u8[16*1024*32]   @ 2375680  (frag-linear fp8 of 16*W; 512 KB)
#define WS_END 2899968

// ---------------- zero counts + accum ----------------
__global__ void k_zero(int* __restrict__ counts, double* __restrict__ accum) {
  const int t = threadIdx.x;
  counts[t] = 0;
  if (t < 8) accum[t] = 0.0;
}

// ---------------- label histogram ----------------
__global__ void k_hist(const int* __restrict__ labels, int* __restrict__ counts) {
  const int i = blockIdx.x * blockDim.x + threadIdx.x;
  if (i < BATCH) atomicAdd(counts + labels[i], 1);
}

// ---------------- exclusive prefix sum over 1024 bins (1 block) ----------------
__global__ void k_scan(const int* __restrict__ counts, int* __restrict__ offsets) {
  __shared__ int tmp[1024];
  const int t = threadIdx.x;
  const int v = counts[t];
  tmp[t] = v;
  __syncthreads();
  for (int d = 1; d < 1024; d <<= 1) {
    int u = (t >= d) ? tmp[t - d] : 0;
    __syncthreads();
    tmp[t] += u;
    __syncthreads();
  }
  offsets[t] = tmp[t] - v;   // exclusive
}

// ---------------- scatter row indices into class-sorted order ----------------
__global__ void k_scatter(const int* __restrict__ labels, int* __restrict__ offsets,
                          int* __restrict__ order) {
  const int i = blockIdx.x * blockDim.x + threadIdx.x;
  if (i < BATCH) {
    const int pos = atomicAdd(offsets + labels[i], 1);
    order[pos] = i;
  }
}

// ---------------- segmented mean -> centers, |center|^2, center-loss (single pass) ----------------
// center loss per (class, col): sum(x - c)^2 = sum(x^2) - cnt * c^2
__global__ void k_segsum(const float* __restrict__ cls, const int* __restrict__ order,
                         const int* __restrict__ offsets, const int* __restrict__ counts,
                         const float* __restrict__ cen_in, float* __restrict__ cen,
                         float* __restrict__ sq, double* __restrict__ accum) {
  __shared__ float red[8];
  __shared__ float redc[8];
  const int c = blockIdx.x;     // 0..1023
  const int t = threadIdx.x;    // 0..511 (one column each)
  const int cnt = counts[c];
  const int end = offsets[c];   // after scatter, offsets[c] == segment end
  const int start = end - cnt;
  float v, cp;
  if (cnt > 0) {
    float s0 = 0.f, s1 = 0.f, s2 = 0.f, s3 = 0.f;
    float q0 = 0.f, q1 = 0.f, q2 = 0.f, q3 = 0.f;
    int i = start;
    for (; i + 4 <= end; i += 4) {
      const int r0 = order[i], r1 = order[i + 1], r2 = order[i + 2], r3 = order[i + 3];
      float x0 = cls[(size_t)r0 * HID + t];
      float x1 = cls[(size_t)r1 * HID + t];
      float x2 = cls[(size_t)r2 * HID + t];
      float x3 = cls[(size_t)r3 * HID + t];
      s0 += x0; q0 = fmaf(x0, x0, q0);
      s1 += x1; q1 = fmaf(x1, x1, q1);
      s2 += x2; q2 = fmaf(x2, x2, q2);
      s3 += x3; q3 = fmaf(x3, x3, q3);
    }
    for (; i < end; ++i) {
      float x = cls[(size_t)order[i] * HID + t];
      s0 += x; q0 = fmaf(x, x, q0);
    }
    v = ((s0 + s1) + (s2 + s3)) / (float)cnt;
    cp = ((q0 + q1) + (q2 + q3)) - (float)cnt * v * v;
  } else {
    v = (c < NCLS) ? cen_in[(size_t)c * HID + t] : 0.f;
    cp = 0.f;
  }
  cen[(size_t)c * HID + t] = v;

  float p = v * v;
  #pragma unroll
  for (int s = 32; s; s >>= 1) { p += __shfl_xor(p, s); cp += __shfl_xor(cp, s); }
  if ((t & 63) == 0) { red[t >> 6] = p; redc[t >> 6] = cp; }
  __syncthreads();
  if (t == 0) {
    float acc = 0.f, accc = 0.f;
    #pragma unroll
    for (int i = 0; i < 8; ++i) { acc += red[i]; accc += redc[i]; }
    sq[c] = acc;
    atomicAdd(accum + 1, (double)accc);
  }
}

// ---------------- W f32 -> fragment-linear fp8 (scaled x16) ----------------
__global__ void k_wconv(const float* __restrict__ W, u32* __restrict__ wb) {
  const int j = blockIdx.x * blockDim.x + threadIdx.x;   // 131072 total
  const int kc = j >> 13, col = (j >> 3) & 1023, kg = (j >> 1) & 3, i0 = (j & 1) * 4;
  const int k = kc * 32 + kg * 8 + i0;
  float w0 = 0.f, w1 = 0.f, w2 = 0.f, w3 = 0.f;
  if (col < NCLS) {
    w0 = W[(size_t)(k + 0) * NCLS + col] * 16.f;
    w1 = W[(size_t)(k + 1) * NCLS + col] * 16.f;
    w2 = W[(size_t)(k + 2) * NCLS + col] * 16.f;
    w3 = W[(size_t)(k + 3) * NCLS + col] * 16.f;
  }
  wb[j] = pk4(w0, w1, w2, w3);
}

// ---------------- separation: Gram + exp-sum ----------------
__global__ void k_sep(const float* __restrict__ cen, const float* __restrict__ sq,
                      double* __restrict__ accum) {
  __shared__ float As[16][64];
  __shared__ float Bs[16][64];
  __shared__ float red[4];
  const int bi = blockIdx.x >> 4, bj = blockIdx.x & 15;
  const int tx = threadIdx.x & 15, ty = threadIdx.x >> 4;
  const int lrow = threadIdx.x & 63, lkq = threadIdx.x >> 6;
  float acc[4][4] = {};
  for (int k0 = 0; k0 < HID; k0 += 16) {
    __syncthreads();
    float4 a = *(const float4*)(cen + (size_t)(bi * 64 + lrow) * HID + k0 + lkq * 4);
    float4 b = *(const float4*)(cen + (size_t)(bj * 64 + lrow) * HID + k0 + lkq * 4);
    As[lkq*4+0][lrow] = a.x; As[lkq*4+1][lrow] = a.y; As[lkq*4+2][lrow] = a.z; As[lkq*4+3][lrow] = a.w;
    Bs[lkq*4+0][lrow] = b.x; Bs[lkq*4+1][lrow] = b.y; Bs[lkq*4+2][lrow] = b.z; Bs[lkq*4+3][lrow] = b.w;
    __syncthreads();
    #pragma unroll
    for (int k = 0; k < 16; ++k) {
      float4 av = *(const float4*)&As[k][ty * 4];
      float4 bv = *(const float4*)&Bs[k][tx * 4];
      float ar[4] = {av.x, av.y, av.z, av.w};
      float br[4] = {bv.x, bv.y, bv.z, bv.w};
      #pragma unroll
      for (int r = 0; r < 4; ++r)
        #pragma unroll
        for (int s = 0; s < 4; ++s)
          acc[r][s] = fmaf(ar[r], br[s], acc[r][s]);
    }
  }
  float part = 0.f;
  #pragma unroll
  for (int r = 0; r < 4; ++r) {
    const int i = bi * 64 + ty * 4 + r;
    #pragma unroll
    for (int s = 0; s < 4; ++s) {
      const int j = bj * 64 + tx * 4 + s;
      if (i < NCLS && j < NCLS) {
        float d2 = fmaxf(sq[i] + sq[j] - 2.f * acc[r][s], 0.f);
        float dist = sqrtf(d2);
        part += __expf((i == j ? 1.f : 0.f) - dist);
      }
    }
  }
  #pragma unroll
  for (int s = 32; s; s >>= 1) part += __shfl_xor(part, s);
  if ((threadIdx.x & 63) == 0) red[threadIdx.x >> 6] = part;
  __syncthreads();
  if (threadIdx.x == 0)
    atomicAdd(accum + 2, (double)(red[0] + red[1] + red[2] + red[3]));
}

// ---------------- fused stab: in-kernel fp8 staging + MFMA + fp8 ln tile + epilogue ----------------
// BM=32 rows/block (2048 blocks), BN=1024, 16 waves x 64 cols, acc[2][4]=32 f32/lane.
// __launch_bounds__(1024,8): cap 64 unified regs -> 2 blocks (32 waves)/CU. LDS 48.5 KB.
// Phase 0: each thread converts 16 elems of (cls + 0.1*noise) to fp8, swizzled, into LDS.
//          (k_prep eliminated: saves 288 MB HBM round-trip + ~45 us kernel; staging
//           latency hidden by 80% occupancy — round-10 counters showed 5x HBM headroom.)
__global__ __launch_bounds__(1024, 8)
void k_gemm(const float* __restrict__ cls, const float* __restrict__ noise,
            const float* __restrict__ logits, const int* __restrict__ labels,
            const float* __restrict__ bias, const u8* __restrict__ wb,
            double* __restrict__ accum) {
  __shared__ u8 Apan[32 * 512];      // 16 KB fp8 A-panel (swizzled)
  __shared__ u8 lntile[32 * 1024];   // 32 KB fp8 ln tile (disjoint from Apan)
  __shared__ float redf[32];
  const int lane = threadIdx.x & 63;
  const int w = threadIdx.x >> 6;    // 0..15
  const int row0 = blockIdx.x * 32;
  const int l15 = lane & 15, lkg = lane >> 4;

  // ---- phase 0: stage 32x512 fp8 A-panel (16 elems/thread, XOR-swizzled dest) ----
  {
    const int row_loc = threadIdx.x >> 5;            // 0..31
    const int k0 = (threadIdx.x & 31) * 16;          // 16 elems per thread
    const int sw = ((row_loc & 7) << 3) | (((row_loc >> 3) & 1) << 6);
    const float* cp = cls   + (size_t)(row0 + row_loc) * HID;
    const float* np = noise + (size_t)(row0 + row_loc) * HID;
    #pragma unroll
    for (int q = 0; q < 2; ++q) {
      const int g = k0 + q * 8;
      const int k = g ^ sw;
      float4 a0 = *(const float4*)(cp + k), a1 = *(const float4*)(cp + k + 4);
      float4 n0 = *(const float4*)(np + k), n1 = *(const float4*)(np + k + 4);
      uint2 p;
      p.x = pk4(fmaf(0.1f, n0.x, a0.x), fmaf(0.1f, n0.y, a0.y),
                fmaf(0.1f, n0.z, a0.z), fmaf(0.1f, n0.w, a0.w));
      p.y = pk4(fmaf(0.1f, n1.x, a1.x), fmaf(0.1f, n1.y, a1.y),
                fmaf(0.1f, n1.z, a1.z), fmaf(0.1f, n1.w, a1.w));
      *(uint2*)&Apan[row_loc * 512 + g] = p;
    }
  }
  __syncthreads();

  // ---- phase 2: 16 barrier-free K-steps (fp8), 64 cols/wave ----
  f32x4 acc[2][4] = {};
  const int swr = ((l15 & 7) << 3) | ((l15 >> 3) << 6);
  for (int kc = 0; kc < 16; ++kc) {
    i64 af0 = *(const i64*)&Apan[(l15)      * 512 + ((kc * 32 + lkg * 8) ^ swr)];
    i64 af1 = *(const i64*)&Apan[(16 + l15) * 512 + ((kc * 32 + lkg * 8) ^ swr)];
    const u8* bb = wb + (size_t)kc * 32768 + (w * 64 + l15) * 32 + lkg * 8;
    #pragma unroll
    for (int ct = 0; ct < 4; ++ct) {
      i64 bf = *(const i64*)(bb + ct * 512);
      acc[0][ct] = __builtin_amdgcn_mfma_f32_16x16x32_fp8_fp8(af0, bf, acc[0][ct], 0, 0, 0);
      acc[1][ct] = __builtin_amdgcn_mfma_f32_16x16x32_fp8_fp8(af1, bf, acc[1][ct], 0, 0, 0);
    }
  }

  // ---- phase 3a: ln = acc/16 + bias -> fp8 into lntile ----
  #pragma unroll
  for (int ct = 0; ct < 4; ++ct) {
    const int col = w * 64 + ct * 16 + l15;
    if (col < NCLS) {
      const float bc = bias[col];
      #pragma unroll
      for (int rt = 0; rt < 2; ++rt) {
        #pragma unroll
        for (int r = 0; r < 4; ++r) {
          const int rowloc = rt * 16 + lkg * 4 + r;
          lntile[rowloc * 1024 + (col ^ ((rowloc & 12) << 2))] =
              pk1(fmaf(acc[rt][ct][r], 0.0625f, bc));
        }
      }
    }
  }
  __syncthreads();

  // ---- phase 3b: single coalesced pass over logits: diff^2 + brier (no max-sub) ----
  float spart = 0.f, bpart = 0.f;
  #pragma unroll
  for (int j = 0; j < 2; ++j) {
    const int rowloc = w * 2 + j;
    const int row = row0 + rowloc;
    const int swz = (rowloc & 12) << 2;
    const u8* lnrow = lntile + rowloc * 1024;
    const float4* lr = (const float4*)(logits + (size_t)row * NCLS);
    const int lab2 = labels[row];
    float S = 0.f, S2 = 0.f, el = 0.f;
    #pragma unroll
    for (int it = 0; it < 4; ++it) {
      const int f = it * 64 + lane;
      if (f < 250) {
        float4 lg = lr[f];
        u32 v = *(const u32*)(lnrow + ((f * 4) ^ swz));
        f32x2 lo = __builtin_amdgcn_cvt_pk_f32_fp8((int)v, false);
        f32x2 hi = __builtin_amdgcn_cvt_pk_f32_fp8((int)v, true);
        float d0 = lo[0] - lg.x, d1 = lo[1] - lg.y, d2 = hi[0] - lg.z, d3 = hi[1] - lg.w;
        spart += d0 * d0 + d1 * d1 + d2 * d2 + d3 * d3;
        float e0 = __expf(lg.x), e1 = __expf(lg.y), e2 = __expf(lg.z), e3 = __expf(lg.w);
        S += e0 + e1 + e2 + e3;
        S2 += e0 * e0 + e1 * e1 + e2 * e2 + e3 * e3;
        const int c0 = f * 4;
        if (c0     == lab2) el = e0;
        if (c0 + 1 == lab2) el = e1;
        if (c0 + 2 == lab2) el = e2;
        if (c0 + 3 == lab2) el = e3;
      }
    }
    #pragma unroll
    for (int s = 32; s; s >>= 1) { S += __shfl_xor(S, s); S2 += __shfl_xor(S2, s); el += __shfl_xor(el, s); }
    bpart += S2 / (S * S) - 2.f * el / S + 1.f;
  }
  #pragma unroll
  for (int s = 32; s; s >>= 1) { spart += __shfl_xor(spart, s); bpart += __shfl_xor(bpart, s); }

  if (lane == 0) { redf[w] = spart; redf[16 + w] = bpart; }
  __syncthreads();
  if (threadIdx.x == 0) {
    float st = 0.f, br = 0.f;
    #pragma unroll
    for (int i = 0; i < 16; ++i) { st += redf[i]; br += redf[16 + i]; }
    atomicAdd(accum + 0, (double)st);
    atomicAdd(accum + 3, (double)br);
  }
}

// ---------------- combine ----------------
__global__ void k_final(const double* __restrict__ accum, float* __restrict__ out) {
  if (threadIdx.x == 0) {
    double stab   = accum[0] / ((double)BATCH * (double)NCLS);
    double center = accum[1] / ((double)BATCH * (double)HID);
    double sep    = accum[2] - (double)NCLS;
    double brier  = accum[3] / (double)BATCH;
    double total  = 1.0 * stab + 0.1 * center + 0.01 * sep + 1.0 * brier;
    out[0] = (float)total;
    out[1] = (float)stab;
    out[2] = (float)center;
    out[3] = (float)sep;
    out[4] = (float)brier;
  }
}

extern "C" void kernel_launch(void* const* d_in, const int* in_sizes, int n_in,
                              void* d_out, int out_size, void* d_ws, size_t ws_size,
                              hipStream_t stream) {
  const float* cls    = (const float*)d_in[0];
  const float* logits = (const float*)d_in[1];
  const int*   labels = (const int*)d_in[2];
  const float* W      = (const float*)d_in[3];
  const float* bias   = (const float*)d_in[4];
  const float* noise  = (const float*)d_in[5];
  const float* cen_in = (const float*)d_in[6];
  float* out = (float*)d_out;
  char* ws = (char*)d_ws;
  if (ws_size < (size_t)WS_END) return;  // fail visibly (out stays poisoned)

  int*    counts  = (int*)(ws + 0);
  double* accum   = (double*)(ws + 4096);
  float*  sq      = (float*)(ws + 8192);
  int*    offsets = (int*)(ws + 12288);
  int*    order   = (int*)(ws + 16384);
  float*  cen     = (float*)(ws + 278528);
  u8*     wb8     = (u8*)(ws + 2375680);

  hipLaunchKernelGGL(k_zero,    dim3(1),    dim3(1024),0, stream, counts, accum);
  hipLaunchKernelGGL(k_hist,    dim3(256),  dim3(256), 0, stream, labels, counts);
  hipLaunchKernelGGL(k_wconv,   dim3(512),  dim3(256), 0, stream, W, (u32*)wb8);
  hipLaunchKernelGGL(k_scan,    dim3(1),    dim3(1024),0, stream, counts, offsets);
  hipLaunchKernelGGL(k_scatter, dim3(256),  dim3(256), 0, stream, labels, offsets, order);
  hipLaunchKernelGGL(k_segsum,  dim3(1024), dim3(512), 0, stream, cls, order, offsets, counts, cen_in, cen, sq, accum);
  hipLaunchKernelGGL(k_sep,     dim3(256),  dim3(256), 0, stream, cen, sq, accum);
  hipLaunchKernelGGL(k_gemm,    dim3(2048), dim3(1024), 0, stream, cls, noise, logits, labels, bias, wb8, accum);
  hipLaunchKernelGGL(k_final,   dim3(1),    dim3(64),  0, stream, accum, out);
}

// Round 12
// 255.928 us; speedup vs baseline: 1.1377x; 1.0880x over previous
//
#include <hip/hip_runtime.h>

#define BATCH 65536
#define HID   512
#define NCLS  1000
#define NCLSP 1024

typedef long i64;   // 8 packed fp8 (2 VGPRs) for MFMA A/B operands
typedef float f32x4 __attribute__((ext_vector_type(4)));
typedef float f32x2 __attribute__((ext_vector_type(2)));
typedef unsigned short u16;
typedef unsigned int u32;
typedef unsigned char u8;

__device__ __forceinline__ u16 f2bf(float f) {
  u32 u = __float_as_uint(f);
  u += 0x7fffu + ((u >> 16) & 1u);
  return (u16)(u >> 16);
}

// pack 4 floats -> 4 fp8 e4m3 bytes (k-order a,b,c,d)
__device__ __forceinline__ u32 pk4(float a, float b, float c, float d) {
  u32 r = 0;
  r = (u32)__builtin_amdgcn_cvt_pk_fp8_f32(a, b, (int)r, false);
  r = (u32)__builtin_amdgcn_cvt_pk_fp8_f32(c, d, (int)r, true);
  return r;
}
__device__ __forceinline__ u8 pk1(float a) {
  return (u8)(__builtin_amdgcn_cvt_pk_fp8_f32(a, 0.f, 0, false) & 0xff);
}

// ---------------- ws layout ----------------
// counts  int[1024]        @ 0
// accum   double[8]        @ 4096   (0 stab, 1 center, 2 sep, 3 brier)
// sq      float[1024]      @ 8192
// offsets int[1024]        @ 12288  (after k_scatter: segment END)
// order   int[65536]       @ 16384
// centers float[1024*512]  @ 278528
// wb8     u8[16*1024*32]   @ 2375680  (frag-linear fp8 of 16*W; 512 KB)
#define WS_END 2899968

// ---------------- zero counts + accum ----------------
__global__ void k_zero(int* __restrict__ counts, double* __restrict__ accum) {
  const int t = threadIdx.x;
  counts[t] = 0;
  if (t < 8) accum[t] = 0.0;
}

// ---------------- label histogram ----------------
__global__ void k_hist(const int* __restrict__ labels, int* __restrict__ counts) {
  const int i = blockIdx.x * blockDim.x + threadIdx.x;
  if (i < BATCH) atomicAdd(counts + labels[i], 1);
}

// ---------------- exclusive prefix sum over 1024 bins (1 block) ----------------
__global__ void k_scan(const int* __restrict__ counts, int* __restrict__ offsets) {
  __shared__ int tmp[1024];
  const int t = threadIdx.x;
  const int v = counts[t];
  tmp[t] = v;
  __syncthreads();
  for (int d = 1; d < 1024; d <<= 1) {
    int u = (t >= d) ? tmp[t - d] : 0;
    __syncthreads();
    tmp[t] += u;
    __syncthreads();
  }
  offsets[t] = tmp[t] - v;   // exclusive
}

// ---------------- scatter row indices into class-sorted order ----------------
__global__ void k_scatter(const int* __restrict__ labels, int* __restrict__ offsets,
                          int* __restrict__ order) {
  const int i = blockIdx.x * blockDim.x + threadIdx.x;
  if (i < BATCH) {
    const int pos = atomicAdd(offsets + labels[i], 1);
    order[pos] = i;
  }
}

// ---------------- segmented mean -> centers, |center|^2, center-loss (single pass) ----------------
// center loss per (class, col): sum(x - c)^2 = sum(x^2) - cnt * c^2
__global__ void k_segsum(const float* __restrict__ cls, const int* __restrict__ order,
                         const int* __restrict__ offsets, const int* __restrict__ counts,
                         const float* __restrict__ cen_in, float* __restrict__ cen,
                         float* __restrict__ sq, double* __restrict__ accum) {
  __shared__ float red[8];
  __shared__ float redc[8];
  const int c = blockIdx.x;     // 0..1023
  const int t = threadIdx.x;    // 0..511 (one column each)
  const int cnt = counts[c];
  const int end = offsets[c];   // after scatter, offsets[c] == segment end
  const int start = end - cnt;
  float v, cp;
  if (cnt > 0) {
    float s0 = 0.f, s1 = 0.f, s2 = 0.f, s3 = 0.f;
    float q0 = 0.f, q1 = 0.f, q2 = 0.f, q3 = 0.f;
    int i = start;
    for (; i + 4 <= end; i += 4) {
      const int r0 = order[i], r1 = order[i + 1], r2 = order[i + 2], r3 = order[i + 3];
      float x0 = cls[(size_t)r0 * HID + t];
      float x1 = cls[(size_t)r1 * HID + t];
      float x2 = cls[(size_t)r2 * HID + t];
      float x3 = cls[(size_t)r3 * HID + t];
      s0 += x0; q0 = fmaf(x0, x0, q0);
      s1 += x1; q1 = fmaf(x1, x1, q1);
      s2 += x2; q2 = fmaf(x2, x2, q2);
      s3 += x3; q3 = fmaf(x3, x3, q3);
    }
    for (; i < end; ++i) {
      float x = cls[(size_t)order[i] * HID + t];
      s0 += x; q0 = fmaf(x, x, q0);
    }
    v = ((s0 + s1) + (s2 + s3)) / (float)cnt;
    cp = ((q0 + q1) + (q2 + q3)) - (float)cnt * v * v;
  } else {
    v = (c < NCLS) ? cen_in[(size_t)c * HID + t] : 0.f;
    cp = 0.f;
  }
  cen[(size_t)c * HID + t] = v;

  float p = v * v;
  #pragma unroll
  for (int s = 32; s; s >>= 1) { p += __shfl_xor(p, s); cp += __shfl_xor(cp, s); }
  if ((t & 63) == 0) { red[t >> 6] = p; redc[t >> 6] = cp; }
  __syncthreads();
  if (t == 0) {
    float acc = 0.f, accc = 0.f;
    #pragma unroll
    for (int i = 0; i < 8; ++i) { acc += red[i]; accc += redc[i]; }
    sq[c] = acc;
    atomicAdd(accum + 1, (double)accc);
  }
}

// ---------------- W f32 -> fragment-linear fp8 (scaled x16) ----------------
__global__ void k_wconv(const float* __restrict__ W, u32* __restrict__ wb) {
  const int j = blockIdx.x * blockDim.x + threadIdx.x;   // 131072 total
  const int kc = j >> 13, col = (j >> 3) & 1023, kg = (j >> 1) & 3, i0 = (j & 1) * 4;
  const int k = kc * 32 + kg * 8 + i0;
  float w0 = 0.f, w1 = 0.f, w2 = 0.f, w3 = 0.f;
  if (col < NCLS) {
    w0 = W[(size_t)(k + 0) * NCLS + col] * 16.f;
    w1 = W[(size_t)(k + 1) * NCLS + col] * 16.f;
    w2 = W[(size_t)(k + 2) * NCLS + col] * 16.f;
    w3 = W[(size_t)(k + 3) * NCLS + col] * 16.f;
  }
  wb[j] = pk4(w0, w1, w2, w3);
}

// ---------------- separation: Gram + exp-sum ----------------
__global__ void k_sep(const float* __restrict__ cen, const float* __restrict__ sq,
                      double* __restrict__ accum) {
  __shared__ float As[16][64];
  __shared__ float Bs[16][64];
  __shared__ float red[4];
  const int bi = blockIdx.x >> 4, bj = blockIdx.x & 15;
  const int tx = threadIdx.x & 15, ty = threadIdx.x >> 4;
  const int lrow = threadIdx.x & 63, lkq = threadIdx.x >> 6;
  float acc[4][4] = {};
  for (int k0 = 0; k0 < HID; k0 += 16) {
    __syncthreads();
    float4 a = *(const float4*)(cen + (size_t)(bi * 64 + lrow) * HID + k0 + lkq * 4);
    float4 b = *(const float4*)(cen + (size_t)(bj * 64 + lrow) * HID + k0 + lkq * 4);
    As[lkq*4+0][lrow] = a.x; As[lkq*4+1][lrow] = a.y; As[lkq*4+2][lrow] = a.z; As[lkq*4+3][lrow] = a.w;
    Bs[lkq*4+0][lrow] = b.x; Bs[lkq*4+1][lrow] = b.y; Bs[lkq*4+2][lrow] = b.z; Bs[lkq*4+3][lrow] = b.w;
    __syncthreads();
    #pragma unroll
    for (int k = 0; k < 16; ++k) {
      float4 av = *(const float4*)&As[k][ty * 4];
      float4 bv = *(const float4*)&Bs[k][tx * 4];
      float ar[4] = {av.x, av.y, av.z, av.w};
      float br[4] = {bv.x, bv.y, bv.z, bv.w};
      #pragma unroll
      for (int r = 0; r < 4; ++r)
        #pragma unroll
        for (int s = 0; s < 4; ++s)
          acc[r][s] = fmaf(ar[r], br[s], acc[r][s]);
    }
  }
  float part = 0.f;
  #pragma unroll
  for (int r = 0; r < 4; ++r) {
    const int i = bi * 64 + ty * 4 + r;
    #pragma unroll
    for (int s = 0; s < 4; ++s) {
      const int j = bj * 64 + tx * 4 + s;
      if (i < NCLS && j < NCLS) {
        float d2 = fmaxf(sq[i] + sq[j] - 2.f * acc[r][s], 0.f);
        float dist = sqrtf(d2);
        part += __expf((i == j ? 1.f : 0.f) - dist);
      }
    }
  }
  #pragma unroll
  for (int s = 32; s; s >>= 1) part += __shfl_xor(part, s);
  if ((threadIdx.x & 63) == 0) red[threadIdx.x >> 6] = part;
  __syncthreads();
  if (threadIdx.x == 0)
    atomicAdd(accum + 2, (double)(red[0] + red[1] + red[2] + red[3]));
}

// ---------------- fused stab: in-kernel fp8 staging + MFMA (B-prefetch) + epilogue ----------------
// BM=32 rows/block (2048 blocks), BN=1024, 16 waves x 64 cols, acc[2][4]=32 f32/lane.
// __launch_bounds__(1024,8): cap 64 unified regs -> 2 blocks (32 waves)/CU. LDS 48.5 KB.
__global__ __launch_bounds__(1024, 8)
void k_gemm(const float* __restrict__ cls, const float* __restrict__ noise,
            const float* __restrict__ logits, const int* __restrict__ labels,
            const float* __restrict__ bias, const u8* __restrict__ wb,
            double* __restrict__ accum) {
  __shared__ u8 Apan[32 * 512];      // 16 KB fp8 A-panel (swizzled)
  __shared__ u8 lntile[32 * 1024];   // 32 KB fp8 ln tile (disjoint from Apan)
  __shared__ float redf[32];
  const int lane = threadIdx.x & 63;
  const int w = threadIdx.x >> 6;    // 0..15
  const int row0 = blockIdx.x * 32;
  const int l15 = lane & 15, lkg = lane >> 4;

  // ---- phase 0: stage 32x512 fp8 A-panel (16 elems/thread, XOR-swizzled dest) ----
  {
    const int row_loc = threadIdx.x >> 5;            // 0..31
    const int k0 = (threadIdx.x & 31) * 16;          // 16 elems per thread
    const int sw = ((row_loc & 7) << 3) | (((row_loc >> 3) & 1) << 6);
    const float* cp = cls   + (size_t)(row0 + row_loc) * HID;
    const float* np = noise + (size_t)(row0 + row_loc) * HID;
    #pragma unroll
    for (int q = 0; q < 2; ++q) {
      const int g = k0 + q * 8;
      const int k = g ^ sw;
      float4 a0 = *(const float4*)(cp + k), a1 = *(const float4*)(cp + k + 4);
      float4 n0 = *(const float4*)(np + k), n1 = *(const float4*)(np + k + 4);
      uint2 p;
      p.x = pk4(fmaf(0.1f, n0.x, a0.x), fmaf(0.1f, n0.y, a0.y),
                fmaf(0.1f, n0.z, a0.z), fmaf(0.1f, n0.w, a0.w));
      p.y = pk4(fmaf(0.1f, n1.x, a1.x), fmaf(0.1f, n1.y, a1.y),
                fmaf(0.1f, n1.z, a1.z), fmaf(0.1f, n1.w, a1.w));
      *(uint2*)&Apan[row_loc * 512 + g] = p;
    }
  }
  __syncthreads();

  // ---- phase 2: 16 K-steps with one-deep register B-prefetch (hide L2 latency) ----
  f32x4 acc[2][4] = {};
  const int swr = ((l15 & 7) << 3) | ((l15 >> 3) << 6);
  const u8* bb0 = wb + (w * 64 + l15) * 32 + lkg * 8;
  i64 bcur[4];
  #pragma unroll
  for (int ct = 0; ct < 4; ++ct) bcur[ct] = *(const i64*)(bb0 + ct * 512);
  for (int kc = 0; kc < 16; ++kc) {
    const int kn = (kc < 15) ? kc + 1 : 15;          // clamped prefetch index (uniform)
    const u8* bbn = bb0 + (size_t)kn * 32768;
    i64 bnxt[4];
    #pragma unroll
    for (int ct = 0; ct < 4; ++ct) bnxt[ct] = *(const i64*)(bbn + ct * 512);
    i64 af0 = *(const i64*)&Apan[(l15)      * 512 + ((kc * 32 + lkg * 8) ^ swr)];
    i64 af1 = *(const i64*)&Apan[(16 + l15) * 512 + ((kc * 32 + lkg * 8) ^ swr)];
    #pragma unroll
    for (int ct = 0; ct < 4; ++ct) {
      acc[0][ct] = __builtin_amdgcn_mfma_f32_16x16x32_fp8_fp8(af0, bcur[ct], acc[0][ct], 0, 0, 0);
      acc[1][ct] = __builtin_amdgcn_mfma_f32_16x16x32_fp8_fp8(af1, bcur[ct], acc[1][ct], 0, 0, 0);
    }
    #pragma unroll
    for (int ct = 0; ct < 4; ++ct) bcur[ct] = bnxt[ct];
  }

  // ---- phase 3a: ln = acc/16 + bias -> fp8 into lntile ----
  #pragma unroll
  for (int ct = 0; ct < 4; ++ct) {
    const int col = w * 64 + ct * 16 + l15;
    if (col < NCLS) {
      const float bc = bias[col];
      #pragma unroll
      for (int rt = 0; rt < 2; ++rt) {
        #pragma unroll
        for (int r = 0; r < 4; ++r) {
          const int rowloc = rt * 16 + lkg * 4 + r;
          lntile[rowloc * 1024 + (col ^ ((rowloc & 12) << 2))] =
              pk1(fmaf(acc[rt][ct][r], 0.0625f, bc));
        }
      }
    }
  }
  __syncthreads();

  // ---- phase 3b: single coalesced pass over logits: diff^2 + brier (no max-sub) ----
  // el read directly: exp(logits[row][lab]) — one broadcast load, no compare chain.
  float spart = 0.f, bpart = 0.f;
  #pragma unroll
  for (int j = 0; j < 2; ++j) {
    const int rowloc = w * 2 + j;
    const int row = row0 + rowloc;
    const int swz = (rowloc & 12) << 2;
    const u8* lnrow = lntile + rowloc * 1024;
    const float4* lr = (const float4*)(logits + (size_t)row * NCLS);
    const int lab2 = labels[row];
    const float el = __expf(logits[(size_t)row * NCLS + lab2]);
    float S = 0.f, S2 = 0.f;
    #pragma unroll
    for (int it = 0; it < 4; ++it) {
      const int f = it * 64 + lane;
      if (f < 250) {
        float4 lg = lr[f];
        u32 v = *(const u32*)(lnrow + ((f * 4) ^ swz));
        f32x2 lo = __builtin_amdgcn_cvt_pk_f32_fp8((int)v, false);
        f32x2 hi = __builtin_amdgcn_cvt_pk_f32_fp8((int)v, true);
        float d0 = lo[0] - lg.x, d1 = lo[1] - lg.y, d2 = hi[0] - lg.z, d3 = hi[1] - lg.w;
        spart += d0 * d0 + d1 * d1 + d2 * d2 + d3 * d3;
        float e0 = __expf(lg.x), e1 = __expf(lg.y), e2 = __expf(lg.z), e3 = __expf(lg.w);
        S += e0 + e1 + e2 + e3;
        S2 += e0 * e0 + e1 * e1 + e2 * e2 + e3 * e3;
      }
    }
    #pragma unroll
    for (int s = 32; s; s >>= 1) { S += __shfl_xor(S, s); S2 += __shfl_xor(S2, s); }
    bpart += S2 / (S * S) - 2.f * el / S + 1.f;
  }
  #pragma unroll
  for (int s = 32; s; s >>= 1) { spart += __shfl_xor(spart, s); bpart += __shfl_xor(bpart, s); }

  if (lane == 0) { redf[w] = spart; redf[16 + w] = bpart; }
  __syncthreads();
  if (threadIdx.x == 0) {
    float st = 0.f, br = 0.f;
    #pragma unroll
    for (int i = 0; i < 16; ++i) { st += redf[i]; br += redf[16 + i]; }
    atomicAdd(accum + 0, (double)st);
    atomicAdd(accum + 3, (double)br);
  }
}

// ---------------- combine ----------------
__global__ void k_final(const double* __restrict__ accum, float* __restrict__ out) {
  if (threadIdx.x == 0) {
    double stab   = accum[0] / ((double)BATCH * (double)NCLS);
    double center = accum[1] / ((double)BATCH * (double)HID);
    double sep    = accum[2] - (double)NCLS;
    double brier  = accum[3] / (double)BATCH;
    double total  = 1.0 * stab + 0.1 * center + 0.01 * sep + 1.0 * brier;
    out[0] = (float)total;
    out[1] = (float)stab;
    out[2] = (float)center;
    out[3] = (float)sep;
    out[4] = (float)brier;
  }
}

extern "C" void kernel_launch(void* const* d_in, const int* in_sizes, int n_in,
                              void* d_out, int out_size, void* d_ws, size_t ws_size,
                              hipStream_t stream) {
  const float* cls    = (const float*)d_in[0];
  const float* logits = (const float*)d_in[1];
  const int*   labels = (const int*)d_in[2];
  const float* W      = (const float*)d_in[3];
  const float* bias   = (const float*)d_in[4];
  const float* noise  = (const float*)d_in[5];
  const float* cen_in = (const float*)d_in[6];
  float* out = (float*)d_out;
  char* ws = (char*)d_ws;
  if (ws_size < (size_t)WS_END) return;  // fail visibly (out stays poisoned)

  int*    counts  = (int*)(ws + 0);
  double* accum   = (double*)(ws + 4096);
  float*  sq      = (float*)(ws + 8192);
  int*    offsets = (int*)(ws + 12288);
  int*    order   = (int*)(ws + 16384);
  float*  cen     = (float*)(ws + 278528);
  u8*     wb8     = (u8*)(ws + 2375680);

  hipLaunchKernelGGL(k_zero,    dim3(1),    dim3(1024),0, stream, counts, accum);
  hipLaunchKernelGGL(k_hist,    dim3(256),  dim3(256), 0, stream, labels, counts);
  hipLaunchKernelGGL(k_wconv,   dim3(512),  dim3(256), 0, stream, W, (u32*)wb8);
  hipLaunchKernelGGL(k_scan,    dim3(1),    dim3(1024),0, stream, counts, offsets);
  hipLaunchKernelGGL(k_scatter, dim3(256),  dim3(256), 0, stream, labels, offsets, order);
  hipLaunchKernelGGL(k_segsum,  dim3(1024), dim3(512), 0, stream, cls, order, offsets, counts, cen_in, cen, sq, accum);
  hipLaunchKernelGGL(k_sep,     dim3(256),  dim3(256), 0, stream, cen, sq, accum);
  hipLaunchKernelGGL(k_gemm,    dim3(2048), dim3(1024), 0, stream, cls, noise, logits, labels, bias, wb8, accum);
  hipLaunchKernelGGL(k_final,   dim3(1),    dim3(64),  0, stream, accum, out);
}